// Round 5
// baseline (683.786 us; speedup 1.0000x reference)
//
#include <hip/hip_runtime.h>

typedef unsigned short u16;
typedef __attribute__((ext_vector_type(8))) short short8;
typedef __attribute__((ext_vector_type(4))) float f32x4;
typedef __attribute__((ext_vector_type(4))) unsigned short u16x4;
typedef __attribute__((ext_vector_type(2))) unsigned u32x2;

#define NN 262144
#define CC 256
#define RR 64
#define GG 1024

// LDS byte-offset swizzle for row-major [node][feat] bf16 tiles: XOR node low
// bits into the 16B-slot bits.
#define SWZ(b, n) ((b) ^ (((n) & 7) << 4))
// slab row-swizzle ([16][64] f32, 256 B rows): XOR row low bits into 16B slot.
#define SSWZ(b, r) ((b) ^ (((r) & 7) << 4))

// ws layout (bytes):
//   0        : 6 bf16 weight matrices, 16384 elems each (w1g,w2g,w1l,w2l,w1a,w2a)
//   196608   : seg float [1024][256]  (raw sums; k_attn scales by 1/cnt)
//   1245184  : cnt int [1024]

static __device__ __forceinline__ u16 f2bf(float f) {
  unsigned u = __builtin_bit_cast(unsigned, f);
  u += 0x7fffu + ((u >> 16) & 1u);   // RNE to bf16
  return (u16)(u >> 16);
}

static __device__ __forceinline__ unsigned cvt_pk_bf16(float lo, float hi) {
  unsigned r;
  asm("v_cvt_pk_bf16_f32 %0, %1, %2" : "=v"(r) : "v"(lo), "v"(hi));
  return r;
}

static __device__ __forceinline__ void lgkm0() {
  __asm__ volatile("s_waitcnt lgkmcnt(0)" ::: "memory");
}

#define MFMA16(a, b, c) __builtin_amdgcn_mfma_f32_16x16x32_bf16((a), (b), (c), 0, 0, 0)

// ---- k_prep: weight cvt (blocks 0..95) + seg/cnt zero (blocks 96..352) ----
__global__ void k_prep(const float* __restrict__ a0, const float* __restrict__ a1,
                       const float* __restrict__ a2, const float* __restrict__ a3,
                       const float* __restrict__ a4, const float* __restrict__ a5,
                       u16* __restrict__ dst, float* __restrict__ zbase) {
  int bid = blockIdx.x;
  if (bid < 96) {
    int m = bid >> 4;
    const float* s = (m == 0) ? a0 : (m == 1) ? a1 : (m == 2) ? a2
                   : (m == 3) ? a3 : (m == 4) ? a4 : a5;
    int off = (((bid & 15) << 8) | threadIdx.x) << 2;
    f32x4 v = *(const f32x4*)(s + off);
    u16x4 p;
    p[0] = f2bf(v[0]); p[1] = f2bf(v[1]); p[2] = f2bf(v[2]); p[3] = f2bf(v[3]);
    *(u16x4*)(dst + m * 16384 + off) = p;
  } else {
    // zero seg (1048576 B) + cnt (4096 B) = 65792 f32x4, 257 blocks x 256 thr
    int idx = (bid - 96) * 256 + threadIdx.x;
    ((f32x4*)zbase)[idx] = (f32x4){0.f, 0.f, 0.f, 0.f};
  }
}

// ============================================================================
// Block = 32 nodes (NT=2), 4 waves, feature-split. LDS = exactly 20480 B ->
// 8 blocks/CU = 32 waves/CU. waves_per_eu(8,8) pins regalloc at <=64 VGPR
// (R3 lesson: unpinned regalloc spills; R4 lesson: 4 blocks/CU is latency-
// starved with serial per-nt chains -> double TLP instead of ILP).
// LDS: x/h 0..16384 ([32][256] bf16 swz; k_glb overlays slabs here after B2);
//      z   16384..20480 ([32][64] bf16 swz).
// ============================================================================
#define ZBOFF 16384

// ---- K1: glb MLP + segment sums/counts ----
__global__ __launch_bounds__(256)
__attribute__((amdgpu_waves_per_eu(8, 8))) void k_glb(
    const float* __restrict__ x, const u16* __restrict__ wbf,
    const int* __restrict__ bidx, const float* __restrict__ pa,
    float* __restrict__ seg, int* __restrict__ cnt) {
  __shared__ __align__(16) char smem[20480];
  const int tid = threadIdx.x;
  const int wave = tid >> 6, lane = tid & 63;
  const int low = lane & 15, quad = lane >> 4;
  const int node0 = blockIdx.x << 5;
  const float alpha = pa[0];
  const u16* w1 = wbf;              // glb_w1 [64][256]
  const u16* w2 = wbf + 16384;      // glb_w2 [256][64]

  const int lbv = bidx[node0 + (lane & 31)];   // lane l holds graph of node l&31

  // ---- stage x -> swizzled bf16 [32][256] ----
  const float* xsrc = x + (size_t)node0 * CC;
#pragma unroll
  for (int k = 0; k < 8; k++) {
    int f = k * 1024 + tid * 4;
    f32x4 v = *(const f32x4*)(xsrc + f);
    int node = f >> 8;
    u32x2 p;
    p[0] = cvt_pk_bf16(v[0], v[1]);
    p[1] = cvt_pk_bf16(v[2], v[3]);
    *(u32x2*)(smem + SWZ(node * 512 + (f & 255) * 2, node)) = p;
  }

  // node counts: wave 0, wave-uniform run-length via shfl (overlaps others'
  // wait at B1)
  if (wave == 0) {
    int cur = __shfl(lbv, 0), rl = 0;
#pragma unroll
    for (int n = 0; n < 32; n++) {
      int b = __shfl(lbv, n);
      if (b != cur) { if (lane == 0) atomicAdd(cnt + cur, rl); rl = 0; cur = b; }
      rl++;
    }
    if (lane == 0) atomicAdd(cnt + cur, rl);
  }
  __syncthreads();   // B1: x visible

  // ---- layer1: wave's 16 feats x 32 nodes ----
  f32x4 z[2] = {};
  const u16* w1p = w1 + (wave * 16 + low) * CC;
#pragma unroll
  for (int ks = 0; ks < 8; ks++) {
    short8 wa = *(const short8*)(w1p + ks * 32 + quad * 8);
#pragma unroll
    for (int nt = 0; nt < 2; nt++) {
      int node = nt * 16 + low;
      short8 xf = *(const short8*)(smem + SWZ(node * 512 + ks * 64 + quad * 16, node));
      z[nt] = MFMA16(wa, xf, z[nt]);
    }
  }
  // PReLU + stage z -> ZB (disjoint from x: no barrier before write)
#pragma unroll
  for (int nt = 0; nt < 2; nt++) {
    float v0 = z[nt][0], v1 = z[nt][1], v2 = z[nt][2], v3 = z[nt][3];
    v0 = v0 >= 0.f ? v0 : alpha * v0;
    v1 = v1 >= 0.f ? v1 : alpha * v1;
    v2 = v2 >= 0.f ? v2 : alpha * v2;
    v3 = v3 >= 0.f ? v3 : alpha * v3;
    int node = nt * 16 + low;
    u32x2 p;
    p[0] = cvt_pk_bf16(v0, v1);
    p[1] = cvt_pk_bf16(v2, v3);
    *(u32x2*)(smem + ZBOFF + SWZ(node * 128 + wave * 32 + quad * 8, node)) = p;
  }
  __syncthreads();   // B2: z visible; x reads drained (slab may overlay x)

  // ---- layer2 + segment reduce, per nt; slab [16][64] f32 row-swizzled ----
  char* slab = smem + wave * 4096;
#pragma unroll
  for (int nt = 0; nt < 2; nt++) {
    int node = nt * 16 + low;
    f32x4 g[4] = {};
#pragma unroll
    for (int ks2 = 0; ks2 < 2; ks2++) {
      short8 zf = *(const short8*)(smem + ZBOFF + SWZ(node * 128 + ks2 * 64 + quad * 16, node));
#pragma unroll
      for (int mt = 0; mt < 4; mt++) {
        short8 wa = *(const short8*)(w2 + (wave * 64 + mt * 16 + low) * RR + ks2 * 32 + quad * 8);
        g[mt] = MFMA16(wa, zf, g[mt]);
      }
    }
#pragma unroll
    for (int mt = 0; mt < 4; mt++)
      *(f32x4*)(slab + SSWZ(low * 256 + mt * 64 + quad * 16, low)) = g[mt];
    lgkm0();
    float acc = 0.f;
    int cur = __shfl(lbv, nt * 16);
#pragma unroll
    for (int n = 0; n < 16; n++) {
      int b = __shfl(lbv, nt * 16 + n);
      if (b != cur) {
        atomicAdd(seg + (size_t)cur * CC + wave * 64 + lane, acc);
        acc = 0.f; cur = b;
      }
      acc += *(const float*)(slab + SSWZ(n * 256 + lane * 4, n));
    }
    atomicAdd(seg + (size_t)cur * CC + wave * 64 + lane, acc);
    lgkm0();   // slab reads drained before next nt overwrites
  }
}

// ---- K3: local MLP + gather(1/cnt fused) + attn MLP + sigmoid ----
__global__ __launch_bounds__(256)
__attribute__((amdgpu_waves_per_eu(8, 8))) void k_attn(
    const float* __restrict__ x, const u16* __restrict__ wbf,
    const int* __restrict__ bidx, const float* __restrict__ seg,
    const int* __restrict__ cnt,
    const float* __restrict__ pal, const float* __restrict__ paa,
    float* __restrict__ out) {
  __shared__ __align__(16) char smem[20480];
  const int tid = threadIdx.x;
  const int wave = tid >> 6, lane = tid & 63;
  const int low = lane & 15, quad = lane >> 4;
  const int node0 = blockIdx.x << 5;
  const float al = pal[0], aa = paa[0];
  const u16* w1l = wbf + 2 * 16384;
  const u16* w2l = wbf + 3 * 16384;
  const u16* w1a = wbf + 4 * 16384;
  const u16* w2a = wbf + 5 * 16384;

  // early: per-node graph id + count (consumed in gather, far later)
  int bb[2], cc[2];
#pragma unroll
  for (int nt = 0; nt < 2; nt++) bb[nt] = bidx[node0 + nt * 16 + low];
#pragma unroll
  for (int nt = 0; nt < 2; nt++) cc[nt] = cnt[bb[nt]];

  // ---- stage x -> swizzled bf16 [32][256] ----
  const float* xsrc = x + (size_t)node0 * CC;
#pragma unroll
  for (int k = 0; k < 8; k++) {
    int f = k * 1024 + tid * 4;
    f32x4 v = *(const f32x4*)(xsrc + f);
    int node = f >> 8;
    u32x2 p;
    p[0] = cvt_pk_bf16(v[0], v[1]);
    p[1] = cvt_pk_bf16(v[2], v[3]);
    *(u32x2*)(smem + SWZ(node * 512 + (f & 255) * 2, node)) = p;
  }
  __syncthreads();   // B1: x visible

  // ---- local layer1 ----
  f32x4 z[2] = {};
  const u16* w1p = w1l + (wave * 16 + low) * CC;
#pragma unroll
  for (int ks = 0; ks < 8; ks++) {
    short8 wa = *(const short8*)(w1p + ks * 32 + quad * 8);
#pragma unroll
    for (int nt = 0; nt < 2; nt++) {
      int node = nt * 16 + low;
      short8 xf = *(const short8*)(smem + SWZ(node * 512 + ks * 64 + quad * 16, node));
      z[nt] = MFMA16(wa, xf, z[nt]);
    }
  }
#pragma unroll
  for (int nt = 0; nt < 2; nt++) {
    float v0 = z[nt][0], v1 = z[nt][1], v2 = z[nt][2], v3 = z[nt][3];
    v0 = v0 >= 0.f ? v0 : al * v0;
    v1 = v1 >= 0.f ? v1 : al * v1;
    v2 = v2 >= 0.f ? v2 : al * v2;
    v3 = v3 >= 0.f ? v3 : al * v3;
    int node = nt * 16 + low;
    u32x2 p;
    p[0] = cvt_pk_bf16(v0, v1);
    p[1] = cvt_pk_bf16(v2, v3);
    *(u32x2*)(smem + ZBOFF + SWZ(node * 128 + wave * 32 + quad * 8, node)) = p;
  }
  __syncthreads();   // B2: z visible; x reads drained (h may overwrite x)

  // ---- layer2 + gather + h-stage, per nt (h -> x region, disjoint from z) ----
#pragma unroll
  for (int nt = 0; nt < 2; nt++) {
    int node = nt * 16 + low;
    f32x4 loc[4] = {};
#pragma unroll
    for (int ks2 = 0; ks2 < 2; ks2++) {
      short8 zf = *(const short8*)(smem + ZBOFF + SWZ(node * 128 + ks2 * 64 + quad * 16, node));
#pragma unroll
      for (int mt = 0; mt < 4; mt++) {
        short8 wa = *(const short8*)(w2l + (wave * 64 + mt * 16 + low) * RR + ks2 * 32 + quad * 8);
        loc[mt] = MFMA16(wa, zf, loc[mt]);
      }
    }
    const float* srow = seg + (size_t)bb[nt] * CC + wave * 64;
    float inv = (cc[nt] > 0) ? __builtin_amdgcn_rcpf((float)cc[nt]) : 0.0f;
#pragma unroll
    for (int mt = 0; mt < 4; mt++) {
      f32x4 sv = *(const f32x4*)(srow + mt * 16 + quad * 4);
      u32x2 p;
      p[0] = cvt_pk_bf16(fmaf(sv[0], inv, loc[mt][0]),
                         fmaf(sv[1], inv, loc[mt][1]));
      p[1] = cvt_pk_bf16(fmaf(sv[2], inv, loc[mt][2]),
                         fmaf(sv[3], inv, loc[mt][3]));
      *(u32x2*)(smem + SWZ(node * 512 + wave * 128 + mt * 32 + quad * 8, node)) = p;
    }
  }
  __syncthreads();   // B3: h visible + z reads drained

  // ---- attn layer1 (B-frags from h); z2 -> ZB (overwrites z) ----
  f32x4 z2[2] = {};
  const u16* w1pa = w1a + (wave * 16 + low) * CC;
#pragma unroll
  for (int ks = 0; ks < 8; ks++) {
    short8 wa = *(const short8*)(w1pa + ks * 32 + quad * 8);
#pragma unroll
    for (int nt = 0; nt < 2; nt++) {
      int node = nt * 16 + low;
      short8 hf = *(const short8*)(smem + SWZ(node * 512 + ks * 64 + quad * 16, node));
      z2[nt] = MFMA16(wa, hf, z2[nt]);
    }
  }
#pragma unroll
  for (int nt = 0; nt < 2; nt++) {
    float v0 = z2[nt][0], v1 = z2[nt][1], v2 = z2[nt][2], v3 = z2[nt][3];
    v0 = v0 >= 0.f ? v0 : aa * v0;
    v1 = v1 >= 0.f ? v1 : aa * v1;
    v2 = v2 >= 0.f ? v2 : aa * v2;
    v3 = v3 >= 0.f ? v3 : aa * v3;
    int node = nt * 16 + low;
    u32x2 p;
    p[0] = cvt_pk_bf16(v0, v1);
    p[1] = cvt_pk_bf16(v2, v3);
    *(u32x2*)(smem + ZBOFF + SWZ(node * 128 + wave * 32 + quad * 8, node)) = p;
  }
  __syncthreads();   // B4: z2 visible

  // ---- attn layer2 + sigmoid + DIRECT store (16 rows x 64 B sectors) ----
#pragma unroll
  for (int nt = 0; nt < 2; nt++) {
    int node = nt * 16 + low;
    f32x4 o[4] = {};
#pragma unroll
    for (int ks2 = 0; ks2 < 2; ks2++) {
      short8 zf = *(const short8*)(smem + ZBOFF + SWZ(node * 128 + ks2 * 64 + quad * 16, node));
#pragma unroll
      for (int mt = 0; mt < 4; mt++) {
        short8 wa = *(const short8*)(w2a + (wave * 64 + mt * 16 + low) * RR + ks2 * 32 + quad * 8);
        o[mt] = MFMA16(wa, zf, o[mt]);
      }
    }
    float* orow = out + (size_t)(node0 + node) * CC + wave * 64;
#pragma unroll
    for (int mt = 0; mt < 4; mt++) {
#pragma unroll
      for (int i = 0; i < 4; i++)
        o[mt][i] = __builtin_amdgcn_rcpf(1.0f + __expf(-o[mt][i]));
      *(f32x4*)(orow + mt * 16 + quad * 4) = o[mt];
    }
  }
}

extern "C" void kernel_launch(void* const* d_in, const int* in_sizes, int n_in,
                              void* d_out, int out_size, void* d_ws, size_t ws_size,
                              hipStream_t stream) {
  (void)in_sizes; (void)n_in; (void)out_size; (void)ws_size;
  const float* x   = (const float*)d_in[0];
  const float* w1g = (const float*)d_in[1];
  const float* ag  = (const float*)d_in[2];
  const float* w2g = (const float*)d_in[3];
  const float* w1l = (const float*)d_in[4];
  const float* al  = (const float*)d_in[5];
  const float* w2l = (const float*)d_in[6];
  const float* w1a = (const float*)d_in[7];
  const float* aa  = (const float*)d_in[8];
  const float* w2a = (const float*)d_in[9];
  const int* bidx  = (const int*)d_in[10];
  float* out = (float*)d_out;

  u16* wbf   = (u16*)d_ws;
  float* seg = (float*)((char*)d_ws + 196608);
  int* cnt   = (int*)((char*)d_ws + 196608 + 1048576);

  k_prep<<<353, 256, 0, stream>>>(w1g, w2g, w1l, w2l, w1a, w2a, wbf, seg);
  k_glb<<<NN / 32, 256, 0, stream>>>(x, wbf, bidx, ag, seg, cnt);
  k_attn<<<NN / 32, 256, 0, stream>>>(x, wbf, bidx, seg, cnt, al, aa, out);
}

// Round 6
// 679.347 us; speedup vs baseline: 1.0065x; 1.0065x over previous
//
#include <hip/hip_runtime.h>

typedef unsigned short u16;
typedef __attribute__((ext_vector_type(8))) short short8;
typedef __attribute__((ext_vector_type(4))) float f32x4;
typedef __attribute__((ext_vector_type(4))) unsigned short u16x4;
typedef __attribute__((ext_vector_type(2))) unsigned u32x2;

#define NN 262144
#define CC 256
#define RR 64
#define GG 1024

// LDS byte-offset swizzle for row-major [node][feat] bf16 tiles: XOR node low
// bits into the 16B-slot bits.
#define SWZ(b, n) ((b) ^ (((n) & 7) << 4))
// slab row-swizzle ([16][64] f32, 256 B rows): XOR row low bits into 16B slot.
#define SSWZ(b, r) ((b) ^ (((r) & 7) << 4))

// ws layout (bytes):
//   0        : 6 bf16 weight matrices, 16384 elems each (w1g,w2g,w1l,w2l,w1a,w2a)
//   196608   : seg float [1024][256]  (raw sums; k_attn scales by 1/cnt)
//   1245184  : cnt int [1024]
//   1249280  : xbf — per-32-node-block PRE-SWIZZLED bf16 x tiles, 16384 B each
//              (only if ws_size permits; k_attn then stages via global_load_lds)
#define XBFOFF 1249280
#define XBFSZ  ((size_t)NN * CC * 2)

static __device__ __forceinline__ u16 f2bf(float f) {
  unsigned u = __builtin_bit_cast(unsigned, f);
  u += 0x7fffu + ((u >> 16) & 1u);   // RNE to bf16
  return (u16)(u >> 16);
}

static __device__ __forceinline__ unsigned cvt_pk_bf16(float lo, float hi) {
  unsigned r;
  asm("v_cvt_pk_bf16_f32 %0, %1, %2" : "=v"(r) : "v"(lo), "v"(hi));
  return r;
}

static __device__ __forceinline__ void lgkm0() {
  __asm__ volatile("s_waitcnt lgkmcnt(0)" ::: "memory");
}

// async global->LDS, 16 B per lane; LDS dest = wave-uniform base + lane*16.
static __device__ __forceinline__ void gload_lds16(const void* g, void* l) {
  __builtin_amdgcn_global_load_lds(
      (const __attribute__((address_space(1))) void*)g,
      (__attribute__((address_space(3))) void*)l, 16, 0, 0);
}

#define MFMA16(a, b, c) __builtin_amdgcn_mfma_f32_16x16x32_bf16((a), (b), (c), 0, 0, 0)

// ---- k_prep: weight cvt (blocks 0..95) + seg/cnt zero (blocks 96..352) ----
__global__ void k_prep(const float* __restrict__ a0, const float* __restrict__ a1,
                       const float* __restrict__ a2, const float* __restrict__ a3,
                       const float* __restrict__ a4, const float* __restrict__ a5,
                       u16* __restrict__ dst, float* __restrict__ zbase) {
  int bid = blockIdx.x;
  if (bid < 96) {
    int m = bid >> 4;
    const float* s = (m == 0) ? a0 : (m == 1) ? a1 : (m == 2) ? a2
                   : (m == 3) ? a3 : (m == 4) ? a4 : a5;
    int off = (((bid & 15) << 8) | threadIdx.x) << 2;
    f32x4 v = *(const f32x4*)(s + off);
    u16x4 p;
    p[0] = f2bf(v[0]); p[1] = f2bf(v[1]); p[2] = f2bf(v[2]); p[3] = f2bf(v[3]);
    *(u16x4*)(dst + m * 16384 + off) = p;
  } else {
    int idx = (bid - 96) * 256 + threadIdx.x;
    ((f32x4*)zbase)[idx] = (f32x4){0.f, 0.f, 0.f, 0.f};
  }
}

// ============================================================================
// Block = 32 nodes (NT=2), 4 waves, feature-split. LDS = 20480 B.
// waves_per_eu(6,6): regalloc target 6 waves/EU -> VGPR budget ~85 (kernel
// needs ~56 -> NO SPILL; R5 lesson: (8,8) budget 64 forced ~150 MB scratch).
// Runtime: 6 blocks/CU = 24 waves/CU (75%).
// LDS: x/h 0..16384 ([32][256] bf16 swz); z 16384..20480 ([32][64] bf16 swz).
// ============================================================================
#define ZBOFF 16384

// ---- K1: glb MLP + segment sums/counts (+ optional xbf tile export) ----
__global__ __launch_bounds__(256)
__attribute__((amdgpu_waves_per_eu(6, 6))) void k_glb(
    const float* __restrict__ x, const u16* __restrict__ wbf,
    const int* __restrict__ bidx, const float* __restrict__ pa,
    float* __restrict__ seg, int* __restrict__ cnt,
    char* __restrict__ xbf) {
  __shared__ __align__(16) char smem[20480];
  const int tid = threadIdx.x;
  const int wave = tid >> 6, lane = tid & 63;
  const int low = lane & 15, quad = lane >> 4;
  const int node0 = blockIdx.x << 5;
  const float alpha = pa[0];
  const u16* w1 = wbf;              // glb_w1 [64][256]
  const u16* w2 = wbf + 16384;      // glb_w2 [256][64]

  const int lbv = bidx[node0 + (lane & 31)];   // lane l holds graph of node l&31

  // ---- stage x -> swizzled bf16 [32][256]; optionally export tile to xbf ----
  const float* xsrc = x + (size_t)node0 * CC;
  char* xtile = xbf ? (xbf + ((size_t)blockIdx.x << 14)) : nullptr;
#pragma unroll
  for (int k = 0; k < 8; k++) {
    int f = k * 1024 + tid * 4;
    f32x4 v = *(const f32x4*)(xsrc + f);
    int node = f >> 8;
    u32x2 p;
    p[0] = cvt_pk_bf16(v[0], v[1]);
    p[1] = cvt_pk_bf16(v[2], v[3]);
    int off = SWZ(node * 512 + (f & 255) * 2, node);
    *(u32x2*)(smem + off) = p;
    if (xtile) *(u32x2*)(xtile + off) = p;   // uniform branch, fire-and-forget
  }

  // node counts: wave 0, wave-uniform run-length via shfl
  if (wave == 0) {
    int cur = __shfl(lbv, 0), rl = 0;
#pragma unroll
    for (int n = 0; n < 32; n++) {
      int b = __shfl(lbv, n);
      if (b != cur) { if (lane == 0) atomicAdd(cnt + cur, rl); rl = 0; cur = b; }
      rl++;
    }
    if (lane == 0) atomicAdd(cnt + cur, rl);
  }
  __syncthreads();   // B1: x visible

  // ---- layer1: wave's 16 feats x 32 nodes ----
  f32x4 z[2] = {};
  const u16* w1p = w1 + (wave * 16 + low) * CC;
#pragma unroll
  for (int ks = 0; ks < 8; ks++) {
    short8 wa = *(const short8*)(w1p + ks * 32 + quad * 8);
#pragma unroll
    for (int nt = 0; nt < 2; nt++) {
      int node = nt * 16 + low;
      short8 xf = *(const short8*)(smem + SWZ(node * 512 + ks * 64 + quad * 16, node));
      z[nt] = MFMA16(wa, xf, z[nt]);
    }
  }
  // PReLU + stage z -> ZB (disjoint from x: no barrier before write)
#pragma unroll
  for (int nt = 0; nt < 2; nt++) {
    float v0 = z[nt][0], v1 = z[nt][1], v2 = z[nt][2], v3 = z[nt][3];
    v0 = v0 >= 0.f ? v0 : alpha * v0;
    v1 = v1 >= 0.f ? v1 : alpha * v1;
    v2 = v2 >= 0.f ? v2 : alpha * v2;
    v3 = v3 >= 0.f ? v3 : alpha * v3;
    int node = nt * 16 + low;
    u32x2 p;
    p[0] = cvt_pk_bf16(v0, v1);
    p[1] = cvt_pk_bf16(v2, v3);
    *(u32x2*)(smem + ZBOFF + SWZ(node * 128 + wave * 32 + quad * 8, node)) = p;
  }
  __syncthreads();   // B2: z visible; x reads drained (slab may overlay x)

  // ---- layer2 + segment reduce, per nt; slab [16][64] f32 row-swizzled ----
  char* slab = smem + wave * 4096;
#pragma unroll
  for (int nt = 0; nt < 2; nt++) {
    int node = nt * 16 + low;
    f32x4 g[4] = {};
#pragma unroll
    for (int ks2 = 0; ks2 < 2; ks2++) {
      short8 zf = *(const short8*)(smem + ZBOFF + SWZ(node * 128 + ks2 * 64 + quad * 16, node));
#pragma unroll
      for (int mt = 0; mt < 4; mt++) {
        short8 wa = *(const short8*)(w2 + (wave * 64 + mt * 16 + low) * RR + ks2 * 32 + quad * 8);
        g[mt] = MFMA16(wa, zf, g[mt]);
      }
    }
#pragma unroll
    for (int mt = 0; mt < 4; mt++)
      *(f32x4*)(slab + SSWZ(low * 256 + mt * 64 + quad * 16, low)) = g[mt];
    lgkm0();
    float acc = 0.f;
    int cur = __shfl(lbv, nt * 16);
#pragma unroll
    for (int n = 0; n < 16; n++) {
      int b = __shfl(lbv, nt * 16 + n);
      if (b != cur) {
        atomicAdd(seg + (size_t)cur * CC + wave * 64 + lane, acc);
        acc = 0.f; cur = b;
      }
      acc += *(const float*)(slab + SSWZ(n * 256 + lane * 4, n));
    }
    atomicAdd(seg + (size_t)cur * CC + wave * 64 + lane, acc);
    lgkm0();   // slab reads drained before next nt overwrites
  }
}

// ---- K3: local MLP + gather(1/cnt fused) + attn MLP + sigmoid ----
// USE_XBF=1: stage x from pre-swizzled bf16 tiles via global_load_lds
// (linear LDS dest + pre-swizzled global source + swizzled reads).
template <int USE_XBF>
__global__ __launch_bounds__(256)
__attribute__((amdgpu_waves_per_eu(6, 6))) void k_attn(
    const float* __restrict__ x, const char* __restrict__ xbf,
    const u16* __restrict__ wbf,
    const int* __restrict__ bidx, const float* __restrict__ seg,
    const int* __restrict__ cnt,
    const float* __restrict__ pal, const float* __restrict__ paa,
    float* __restrict__ out) {
  __shared__ __align__(16) char smem[20480];
  const int tid = threadIdx.x;
  const int wave = tid >> 6, lane = tid & 63;
  const int low = lane & 15, quad = lane >> 4;
  const int node0 = blockIdx.x << 5;
  const float al = pal[0], aa = paa[0];
  const u16* w1l = wbf + 2 * 16384;
  const u16* w2l = wbf + 3 * 16384;
  const u16* w1a = wbf + 4 * 16384;
  const u16* w2a = wbf + 5 * 16384;

  // ---- stage x tile ----
  if (USE_XBF) {
    const char* gsrc = xbf + ((size_t)blockIdx.x << 14) + wave * 1024 + lane * 16;
    char* ldst = smem + wave * 1024 + lane * 16;
#pragma unroll
    for (int i = 0; i < 4; i++)
      gload_lds16(gsrc + i * 4096, ldst + i * 4096);
  }

  // early: per-node graph id + count (consumed in gather, far later)
  int bb[2], cc[2];
#pragma unroll
  for (int nt = 0; nt < 2; nt++) bb[nt] = bidx[node0 + nt * 16 + low];
#pragma unroll
  for (int nt = 0; nt < 2; nt++) cc[nt] = cnt[bb[nt]];

  if (!USE_XBF) {
    const float* xsrc = x + (size_t)node0 * CC;
#pragma unroll
    for (int k = 0; k < 8; k++) {
      int f = k * 1024 + tid * 4;
      f32x4 v = *(const f32x4*)(xsrc + f);
      int node = f >> 8;
      u32x2 p;
      p[0] = cvt_pk_bf16(v[0], v[1]);
      p[1] = cvt_pk_bf16(v[2], v[3]);
      *(u32x2*)(smem + SWZ(node * 512 + (f & 255) * 2, node)) = p;
    }
  }
  __syncthreads();   // B1: x visible (implies vmcnt(0) drain for global_load_lds)

  // ---- local layer1 ----
  f32x4 z[2] = {};
  const u16* w1p = w1l + (wave * 16 + low) * CC;
#pragma unroll
  for (int ks = 0; ks < 8; ks++) {
    short8 wa = *(const short8*)(w1p + ks * 32 + quad * 8);
#pragma unroll
    for (int nt = 0; nt < 2; nt++) {
      int node = nt * 16 + low;
      short8 xf = *(const short8*)(smem + SWZ(node * 512 + ks * 64 + quad * 16, node));
      z[nt] = MFMA16(wa, xf, z[nt]);
    }
  }
#pragma unroll
  for (int nt = 0; nt < 2; nt++) {
    float v0 = z[nt][0], v1 = z[nt][1], v2 = z[nt][2], v3 = z[nt][3];
    v0 = v0 >= 0.f ? v0 : al * v0;
    v1 = v1 >= 0.f ? v1 : al * v1;
    v2 = v2 >= 0.f ? v2 : al * v2;
    v3 = v3 >= 0.f ? v3 : al * v3;
    int node = nt * 16 + low;
    u32x2 p;
    p[0] = cvt_pk_bf16(v0, v1);
    p[1] = cvt_pk_bf16(v2, v3);
    *(u32x2*)(smem + ZBOFF + SWZ(node * 128 + wave * 32 + quad * 8, node)) = p;
  }
  __syncthreads();   // B2: z visible; x reads drained (h may overwrite x)

  // ---- layer2 + gather + h-stage, per nt (h -> x region, disjoint from z) ----
#pragma unroll
  for (int nt = 0; nt < 2; nt++) {
    int node = nt * 16 + low;
    f32x4 loc[4] = {};
#pragma unroll
    for (int ks2 = 0; ks2 < 2; ks2++) {
      short8 zf = *(const short8*)(smem + ZBOFF + SWZ(node * 128 + ks2 * 64 + quad * 16, node));
#pragma unroll
      for (int mt = 0; mt < 4; mt++) {
        short8 wa = *(const short8*)(w2l + (wave * 64 + mt * 16 + low) * RR + ks2 * 32 + quad * 8);
        loc[mt] = MFMA16(wa, zf, loc[mt]);
      }
    }
    const float* srow = seg + (size_t)bb[nt] * CC + wave * 64;
    float inv = (cc[nt] > 0) ? __builtin_amdgcn_rcpf((float)cc[nt]) : 0.0f;
#pragma unroll
    for (int mt = 0; mt < 4; mt++) {
      f32x4 sv = *(const f32x4*)(srow + mt * 16 + quad * 4);
      u32x2 p;
      p[0] = cvt_pk_bf16(fmaf(sv[0], inv, loc[mt][0]),
                         fmaf(sv[1], inv, loc[mt][1]));
      p[1] = cvt_pk_bf16(fmaf(sv[2], inv, loc[mt][2]),
                         fmaf(sv[3], inv, loc[mt][3]));
      *(u32x2*)(smem + SWZ(node * 512 + wave * 128 + mt * 32 + quad * 8, node)) = p;
    }
  }
  __syncthreads();   // B3: h visible + z reads drained

  // ---- attn layer1 (B-frags from h); z2 -> ZB (overwrites z) ----
  f32x4 z2[2] = {};
  const u16* w1pa = w1a + (wave * 16 + low) * CC;
#pragma unroll
  for (int ks = 0; ks < 8; ks++) {
    short8 wa = *(const short8*)(w1pa + ks * 32 + quad * 8);
#pragma unroll
    for (int nt = 0; nt < 2; nt++) {
      int node = nt * 16 + low;
      short8 hf = *(const short8*)(smem + SWZ(node * 512 + ks * 64 + quad * 16, node));
      z2[nt] = MFMA16(wa, hf, z2[nt]);
    }
  }
#pragma unroll
  for (int nt = 0; nt < 2; nt++) {
    float v0 = z2[nt][0], v1 = z2[nt][1], v2 = z2[nt][2], v3 = z2[nt][3];
    v0 = v0 >= 0.f ? v0 : aa * v0;
    v1 = v1 >= 0.f ? v1 : aa * v1;
    v2 = v2 >= 0.f ? v2 : aa * v2;
    v3 = v3 >= 0.f ? v3 : aa * v3;
    int node = nt * 16 + low;
    u32x2 p;
    p[0] = cvt_pk_bf16(v0, v1);
    p[1] = cvt_pk_bf16(v2, v3);
    *(u32x2*)(smem + ZBOFF + SWZ(node * 128 + wave * 32 + quad * 8, node)) = p;
  }
  __syncthreads();   // B4: z2 visible

  // ---- attn layer2 + sigmoid + DIRECT store (16 rows x 64 B sectors) ----
#pragma unroll
  for (int nt = 0; nt < 2; nt++) {
    int node = nt * 16 + low;
    f32x4 o[4] = {};
#pragma unroll
    for (int ks2 = 0; ks2 < 2; ks2++) {
      short8 zf = *(const short8*)(smem + ZBOFF + SWZ(node * 128 + ks2 * 64 + quad * 16, node));
#pragma unroll
      for (int mt = 0; mt < 4; mt++) {
        short8 wa = *(const short8*)(w2a + (wave * 64 + mt * 16 + low) * RR + ks2 * 32 + quad * 8);
        o[mt] = MFMA16(wa, zf, o[mt]);
      }
    }
    float* orow = out + (size_t)(node0 + node) * CC + wave * 64;
#pragma unroll
    for (int mt = 0; mt < 4; mt++) {
#pragma unroll
      for (int i = 0; i < 4; i++)
        o[mt][i] = __builtin_amdgcn_rcpf(1.0f + __expf(-o[mt][i]));
      *(f32x4*)(orow + mt * 16 + quad * 4) = o[mt];
    }
  }
}

extern "C" void kernel_launch(void* const* d_in, const int* in_sizes, int n_in,
                              void* d_out, int out_size, void* d_ws, size_t ws_size,
                              hipStream_t stream) {
  (void)in_sizes; (void)n_in; (void)out_size;
  const float* x   = (const float*)d_in[0];
  const float* w1g = (const float*)d_in[1];
  const float* ag  = (const float*)d_in[2];
  const float* w2g = (const float*)d_in[3];
  const float* w1l = (const float*)d_in[4];
  const float* al  = (const float*)d_in[5];
  const float* w2l = (const float*)d_in[6];
  const float* w1a = (const float*)d_in[7];
  const float* aa  = (const float*)d_in[8];
  const float* w2a = (const float*)d_in[9];
  const int* bidx  = (const int*)d_in[10];
  float* out = (float*)d_out;

  u16* wbf   = (u16*)d_ws;
  float* seg = (float*)((char*)d_ws + 196608);
  int* cnt   = (int*)((char*)d_ws + 196608 + 1048576);
  const bool big = ws_size >= (size_t)XBFOFF + XBFSZ;
  char* xbf  = big ? ((char*)d_ws + XBFOFF) : nullptr;

  k_prep<<<353, 256, 0, stream>>>(w1g, w2g, w1l, w2l, w1a, w2a, wbf, seg);
  k_glb<<<NN / 32, 256, 0, stream>>>(x, wbf, bidx, ag, seg, cnt, xbf);
  if (big)
    k_attn<1><<<NN / 32, 256, 0, stream>>>(x, xbf, wbf, bidx, seg, cnt, al, aa, out);
  else
    k_attn<0><<<NN / 32, 256, 0, stream>>>(x, xbf, wbf, bidx, seg, cnt, al, aa, out);
}